// Round 5
// baseline (349.099 us; speedup 1.0000x reference)
//
#include <hip/hip_runtime.h>
#include <hip/hip_bf16.h>

#define SEQ    4096
#define SCALE  0.125f

typedef __attribute__((ext_vector_type(8))) short s8v;
typedef __attribute__((ext_vector_type(4))) float f4v;

__device__ __forceinline__ unsigned short f2bf(float f){
  unsigned int u = __builtin_bit_cast(unsigned int, f);
  u += 0x7FFFu + ((u >> 16) & 1u);
  return (unsigned short)(u >> 16);
}

typedef const __attribute__((address_space(1))) unsigned int gl_uint;
typedef __attribute__((address_space(3))) unsigned int lds_uint;

__device__ __forceinline__ void gload_lds16(const unsigned short* g, unsigned short* l){
  __builtin_amdgcn_global_load_lds((gl_uint*)g, (lds_uint*)l, 16, 0, 0);
}

#define MM(a,b,c) __builtin_amdgcn_mfma_f32_16x16x32_bf16(a,b,c,0,0,0)
#define BAR() __builtin_amdgcn_s_barrier()
#define SB0() __builtin_amdgcn_sched_barrier(0)
#define VMW(n) asm volatile("s_waitcnt vmcnt(" #n ")" ::: "memory")

__device__ __forceinline__ void mfmaH0(const s8v (&A)[8], const s8v (&B)[4], f4v (&acc)[8][4]){
#pragma unroll
  for (int m = 0; m < 4; m++)
#pragma unroll
    for (int n = 0; n < 4; n++) acc[m][n] = MM(A[m], B[n], acc[m][n]);
}
__device__ __forceinline__ void mfmaH1(const s8v (&A)[8], const s8v (&B)[4], f4v (&acc)[8][4]){
#pragma unroll
  for (int m = 4; m < 8; m++)
#pragma unroll
    for (int n = 0; n < 4; n++) acc[m][n] = MM(A[m], B[n], acc[m][n]);
}

// ---------------- 256x256-tile GEMM mainloop, K=1024, BK=32, 8 waves (2Mx4N).
// 4-deep LDS ring (4 x (A 16KB + B 16KB) = 128 KiB). ONE barrier per K-tile.
// BODY(t): VMW(4); BAR; stage tile t+3; ds_read tile t+1 frags (banked regs);
//          MFMA tile t (two half-clusters so A_cur[0..3] dies before A_nxt[4..7]
//          loads -> max-live fits 2 waves/SIMD).
// Reads of t+1 overlap MFMA(t); compiler inserts counted lgkmcnt for the
// MFMA(t) operand deps (loaded in BODY(t-1)) -- no manual lgkm drain needed.
// Safety: slot (t-1) overwrite by STG(t+3) is safe because every wave's
// slot-(t-1) reads were waitcnt-drained before MFMA(t-1) (pre-barrier, program
// order), so all drained at BODY(t)'s barrier. VMW(4) before BAR guarantees
// tile t+1 resident in LDS across all waves before any post-barrier read.
// LDS chunk swizzle (verified round 4: SQ_LDS_BANK_CONFLICT == 0):
//   content at [row r][slot c] = chunk c^((r>>1)&3); reader quad q reads slot
//   q^((r>>1)&3); staging thread t fetches global chunk (t&3)^((t>>3)&3).
__device__ __forceinline__ void mainloop_256(
    const unsigned short* __restrict__ Ag,
    const unsigned short* __restrict__ Bg,
    int bm, int bn, f4v (&acc)[8][4])
{
  __shared__ __align__(16) unsigned short lds[65536];   // 128 KiB
  const int tid  = threadIdx.x;
  const int wave = tid >> 6, lane = tid & 63;
  const int quad = lane >> 4, l16 = lane & 15;
  const int wmi  = wave >> 2, wni = wave & 3;
  const char* ldsc = (const char*)lds;

  const int c16   = (quad ^ ((l16 >> 1) & 3)) * 16;     // byte chunk offset
  const int abase = (wmi * 128 + l16) * 64 + c16;       // bytes within slot
  const int bbase = 16384 + (wni * 64 + l16) * 64 + c16;

  const int schunk = (((tid & 3) ^ ((tid >> 3) & 3)) * 8);
  const unsigned short* aS = Ag + (size_t)(bm + (tid >> 2)) * 1024 + schunk;
  const unsigned short* bS = Bg + (size_t)(bn + (tid >> 2)) * 1024 + schunk;
  unsigned short* ldsw = lds + wave * 512;   // wave-uniform gload_lds base

#define STG_A(t_) do{ unsigned short* d_ = ldsw + ((t_) & 3) * 16384; \
    const unsigned short* s_ = aS + (t_) * 32; \
    gload_lds16(s_, d_); gload_lds16(s_ + 128 * 1024, d_ + 4096); }while(0)
#define STG_B(t_) do{ unsigned short* d_ = ldsw + ((t_) & 3) * 16384 + 8192; \
    const unsigned short* s_ = bS + (t_) * 32; \
    gload_lds16(s_, d_); gload_lds16(s_ + 128 * 1024, d_ + 4096); }while(0)

#define LD_B4(NB, base_) do{ \
    NB[0] = *(const s8v*)((base_) + bbase);        NB[1] = *(const s8v*)((base_) + bbase + 1024); \
    NB[2] = *(const s8v*)((base_) + bbase + 2048); NB[3] = *(const s8v*)((base_) + bbase + 3072); }while(0)
#define LD_A4LO(NA, base_) do{ \
    NA[0] = *(const s8v*)((base_) + abase);        NA[1] = *(const s8v*)((base_) + abase + 1024); \
    NA[2] = *(const s8v*)((base_) + abase + 2048); NA[3] = *(const s8v*)((base_) + abase + 3072); }while(0)
#define LD_A4HI(NA, base_) do{ \
    NA[4] = *(const s8v*)((base_) + abase + 4096); NA[5] = *(const s8v*)((base_) + abase + 5120); \
    NA[6] = *(const s8v*)((base_) + abase + 6144); NA[7] = *(const s8v*)((base_) + abase + 7168); }while(0)

  s8v A0[8], B0[4], A1[8], B1[4];

  // prologue: stage tiles 0,1,2 (12 vmem ops); retire tile 0; read its frags
  STG_A(0); STG_B(0); STG_A(1); STG_B(1); STG_A(2); STG_B(2);
  VMW(8); BAR();
  LD_B4(B0, ldsc); LD_A4LO(A0, ldsc); LD_A4HI(A0, ldsc);

#define BODY(T_, CA, CB, NA, NB, DOSTG, VMWx) do{ \
    VMWx; BAR(); SB0(); \
    if (DOSTG){ STG_A((T_) + 3); STG_B((T_) + 3); } \
    { const char* nb_ = ldsc + ((((T_) + 1) & 3) << 15); \
      LD_B4(NB, nb_); LD_A4LO(NA, nb_); \
      __builtin_amdgcn_s_setprio(1); mfmaH0(CA, CB, acc); __builtin_amdgcn_s_setprio(0); \
      LD_A4HI(NA, nb_); \
      __builtin_amdgcn_s_setprio(1); mfmaH1(CA, CB, acc); __builtin_amdgcn_s_setprio(0); } \
  }while(0)

  // vmcnt ledger: 4 ops/K-tile. At BODY(t): outstanding = tiles t+1,t+2 (8);
  // VMW(4) retires tile t+1 before its ds_reads. STG(t+3) -> back to 8.
  for (int t = 0; t < 28; t += 2){
    BODY(t,     A0, B0, A1, B1, 1, VMW(4));
    BODY(t + 1, A1, B1, A0, B0, 1, VMW(4));
  }
  BODY(28, A0, B0, A1, B1, 1, VMW(4));   // stages tile 31 (last)
  BODY(29, A1, B1, A0, B0, 0, VMW(4));   // retire tile 30
  BODY(30, A0, B0, A1, B1, 0, VMW(0));   // retire tile 31
  // tile 31 (frags in A1/B1; compiler inserts the lgkm wait)
  __builtin_amdgcn_s_setprio(1);
  mfmaH0(A1, B1, acc); mfmaH1(A1, B1, acc);
  __builtin_amdgcn_s_setprio(0);

#undef BODY
#undef LD_B4
#undef LD_A4LO
#undef LD_A4HI
#undef STG_A
#undef STG_B
}

// ---------------- qkv GEMM (fused q-softmax + k-exp), 256x256 tile
__global__ __launch_bounds__(512, 2) void qkv_gemm(
    const unsigned short* __restrict__ A,
    const unsigned short* __restrict__ Bt,
    unsigned short* __restrict__ qt,
    unsigned short* __restrict__ kt,
    unsigned short* __restrict__ vb)
{
  const int id  = blockIdx.x;
  const int swz = (id & 7) * 96 + (id >> 3);     // 768 blocks, bijective XCD swizzle
  const int bm  = (swz / 12) * 256, bn = (swz % 12) * 256;

  f4v acc[8][4];
#pragma unroll
  for (int i = 0; i < 8; i++)
#pragma unroll
    for (int j = 0; j < 4; j++) acc[i][j] = (f4v){0.f,0.f,0.f,0.f};

  mainloop_256(A, Bt, bm, bn, acc);

  const int tid = threadIdx.x;
  const int wave = tid >> 6, lane = tid & 63;
  const int quad = lane >> 4, l16 = lane & 15;
  const int wmi = wave >> 2, wni = wave & 3;
  const int colbase = bn + wni * 64;             // 64-aligned -> one head per wave
  const int rowbase = bm + wmi * 128;
  const int sec = colbase >> 10;                 // 0=q 1=k 2=v (wave-uniform)

  if (sec == 2){
#pragma unroll
    for (int nf = 0; nf < 4; nf++){
      int vc = colbase + nf * 16 + l16 - 2048;
#pragma unroll
      for (int mf = 0; mf < 8; mf++){
        int row = rowbase + mf * 16 + quad * 4;
#pragma unroll
        for (int r = 0; r < 4; r++)
          vb[(size_t)(row + r) * 1024 + vc] = f2bf(acc[mf][nf][r]);
      }
    }
    return;
  }

  if (sec == 0){
    // fused softmax over d (wave's 64 cols = full head)
#pragma unroll
    for (int mf = 0; mf < 8; mf++){
#pragma unroll
      for (int r = 0; r < 4; r++){
        float m = fmaxf(fmaxf(acc[mf][0][r], acc[mf][1][r]),
                        fmaxf(acc[mf][2][r], acc[mf][3][r]));
        for (int off = 8; off; off >>= 1) m = fmaxf(m, __shfl_xor(m, off));
        m *= SCALE;
        float e0 = __expf(acc[mf][0][r] * SCALE - m);
        float e1 = __expf(acc[mf][1][r] * SCALE - m);
        float e2 = __expf(acc[mf][2][r] * SCALE - m);
        float e3 = __expf(acc[mf][3][r] * SCALE - m);
        float s = (e0 + e1) + (e2 + e3);
        for (int off = 8; off; off >>= 1) s += __shfl_xor(s, off);
        float inv = 1.f / s;
        acc[mf][0][r] = e0 * inv; acc[mf][1][r] = e1 * inv;
        acc[mf][2][r] = e2 * inv; acc[mf][3][r] = e3 * inv;
      }
    }
#pragma unroll
    for (int nf = 0; nf < 4; nf++){
      int col = colbase + nf * 16 + l16;
      int h = (col >> 6) & 15, de = col & 63;
#pragma unroll
      for (int mf = 0; mf < 8; mf++){
        int row = rowbase + mf * 16 + quad * 4;
        int bb = row >> 12, nl = row & 4095;
        ushort4 o;
        o.x = f2bf(acc[mf][nf][0]); o.y = f2bf(acc[mf][nf][1]);
        o.z = f2bf(acc[mf][nf][2]); o.w = f2bf(acc[mf][nf][3]);
        *(ushort4*)&qt[(((size_t)bb * 16 + h) * 64 + de) * SEQ + nl] = o;
      }
    }
  } else {
    // k: exp per element; normalizer recovered in ctx2 (q cols sum to 1)
#pragma unroll
    for (int nf = 0; nf < 4; nf++){
      int col = colbase + nf * 16 + l16;
      int h = (col >> 6) & 15, de = col & 63;
#pragma unroll
      for (int mf = 0; mf < 8; mf++){
        int row = rowbase + mf * 16 + quad * 4;
        int bb = row >> 12, nl = row & 4095;
        ushort4 o;
        o.x = f2bf(__expf(acc[mf][nf][0])); o.y = f2bf(__expf(acc[mf][nf][1]));
        o.z = f2bf(__expf(acc[mf][nf][2])); o.w = f2bf(__expf(acc[mf][nf][3]));
        *(ushort4*)&kt[(((size_t)bb * 16 + h) * 64 + de) * SEQ + nl] = o;
      }
    }
  }
}

// ---------------- final batched GEMM: out[b] = vb[b] @ ctx2t[b]^T + bias, fp32
__global__ __launch_bounds__(512, 2) void gemm_final(
    const unsigned short* __restrict__ A,
    const unsigned short* __restrict__ C2t,
    float* __restrict__ Cf,
    const float* __restrict__ bias)
{
  const int id  = blockIdx.x;
  const int swz = (id & 7) * 32 + (id >> 3);     // 256 blocks, bijective XCD swizzle
  const int bm  = (swz >> 2) * 256, bn = (swz & 3) * 256;
  const unsigned short* Bt = C2t + (size_t)(bm >> 12) * 1024 * 1024;

  f4v acc[8][4];
#pragma unroll
  for (int i = 0; i < 8; i++)
#pragma unroll
    for (int j = 0; j < 4; j++) acc[i][j] = (f4v){0.f,0.f,0.f,0.f};

  mainloop_256(A, Bt, bm, bn, acc);

  const int tid = threadIdx.x;
  const int wave = tid >> 6, lane = tid & 63;
  const int quad = lane >> 4, l16 = lane & 15;
  const int wmi = wave >> 2, wni = wave & 3;

#pragma unroll
  for (int nf = 0; nf < 4; nf++){
    int col = bn + wni * 64 + nf * 16 + l16;
    float bv = bias[col];
#pragma unroll
    for (int mf = 0; mf < 8; mf++){
      int row = bm + wmi * 128 + mf * 16 + quad * 4;
#pragma unroll
      for (int r = 0; r < 4; r++)
        Cf[(size_t)(row + r) * 1024 + col] = acc[mf][nf][r] + bv;
    }
  }
}

// ---------------- fp32 -> bf16 elementwise (4/thread)
__global__ void cvt_f32_bf16(const float4* __restrict__ in, ushort4* __restrict__ outp){
  int i = blockIdx.x * 256 + threadIdx.x;
  float4 v = in[i];
  ushort4 o;
  o.x = f2bf(v.x); o.y = f2bf(v.y); o.z = f2bf(v.z); o.w = f2bf(v.w);
  outp[i] = o;
}

// ---------------- transpose + cvt: in[R,C] fp32 -> out[C,R] bf16
__global__ __launch_bounds__(256) void transpose_cvt(const float* __restrict__ in,
                                                     unsigned short* __restrict__ outp,
                                                     int R, int C){
  __shared__ float tile[64][65];
  int r0 = blockIdx.y * 64, c0 = blockIdx.x * 64;
  int t = threadIdx.x;
  for (int i = t; i < 4096; i += 256){ int r = i >> 6, c = i & 63;
    tile[r][c] = in[(size_t)(r0 + r) * C + c0 + c]; }
  __syncthreads();
  for (int i = t; i < 4096; i += 256){ int c = i >> 6, r = i & 63;
    outp[(size_t)(c0 + c) * R + r0 + r] = f2bf(tile[r][c]); }
}

// ---------------- ctx partial: ctxp[bh*4+chunk][d*64+e] = sum_{n in chunk} qt[d,n] kt[e,n]
__global__ __launch_bounds__(256) void ctx_partial(const unsigned short* __restrict__ qt,
                                                   const unsigned short* __restrict__ kt,
                                                   float* __restrict__ ctxp){
  __shared__ float red[4096];
  int bh = blockIdx.x >> 2, ch = blockIdx.x & 3;
  int t = threadIdx.x, wave = t >> 6, lane = t & 63, quad = lane >> 4, l16 = lane & 15;
  const unsigned short* qb = qt + (size_t)bh * 64 * SEQ;
  const unsigned short* kb = kt + (size_t)bh * 64 * SEQ;
  f4v acc[4][4];
#pragma unroll
  for (int i = 0; i < 4; i++)
#pragma unroll
    for (int j = 0; j < 4; j++) acc[i][j] = (f4v){0.f,0.f,0.f,0.f};
  int ns = ch * 1024 + wave * 256;
  for (int n0 = ns; n0 < ns + 256; n0 += 32){
    s8v af[4], bf[4];
#pragma unroll
    for (int mt = 0; mt < 4; mt++) af[mt] = *(const s8v*)&qb[(size_t)(mt*16 + l16) * SEQ + n0 + quad*8];
#pragma unroll
    for (int nt = 0; nt < 4; nt++) bf[nt] = *(const s8v*)&kb[(size_t)(nt*16 + l16) * SEQ + n0 + quad*8];
#pragma unroll
    for (int mt = 0; mt < 4; mt++)
#pragma unroll
      for (int nt = 0; nt < 4; nt++)
        acc[mt][nt] = __builtin_amdgcn_mfma_f32_16x16x32_bf16(af[mt], bf[nt], acc[mt][nt], 0, 0, 0);
  }
  for (int i = t; i < 4096; i += 256) red[i] = 0.f;
  __syncthreads();
  for (int w = 0; w < 4; w++){
    if (wave == w){
#pragma unroll
      for (int mt = 0; mt < 4; mt++)
#pragma unroll
        for (int nt = 0; nt < 4; nt++)
#pragma unroll
          for (int r = 0; r < 4; r++)
            red[(mt*16 + quad*4 + r) * 64 + nt*16 + l16] += acc[mt][nt][r];
    }
    __syncthreads();
  }
  float* cp = ctxp + (size_t)blockIdx.x * 4096;
  for (int i = t; i < 4096; i += 256) cp[i] = red[i];
}

// ---------------- ctx2t[b][f][h*64+d] = sum_e ctx[d][e]*inv[e] * w_out[h*64+e][f]  (bf16 out)
__global__ __launch_bounds__(256) void ctx2_kernel(const float* __restrict__ ctxp,
                                                   const float* __restrict__ w_out,
                                                   unsigned short* __restrict__ ctx2t){
  __shared__ float ctxs[4096];
  __shared__ float inv_s[64];
  int bh = blockIdx.x >> 4, fc = blockIdx.x & 15;
  int b = bh >> 4, h = bh & 15;
  int t = threadIdx.x;
  int fl = t & 63, dg = t >> 6;
  int f = fc * 64 + fl;
  for (int i = t; i < 4096; i += 256){
    const float* p = ctxp + (size_t)bh * 4 * 4096 + i;
    ctxs[i] = (p[0] + p[4096]) + (p[8192] + p[12288]);
  }
  __syncthreads();
  if (t < 64){
    float s = 0.f;
#pragma unroll
    for (int d = 0; d < 64; d++) s += ctxs[d * 64 + t];
    inv_s[t] = 1.f / s;
  }
  __syncthreads();
  float acc[16];
#pragma unroll
  for (int i = 0; i < 16; i++) acc[i] = 0.f;
  for (int e = 0; e < 64; e++){
    float w = w_out[(size_t)(h * 64 + e) * 1024 + f] * inv_s[e];
#pragma unroll
    for (int dd = 0; dd < 16; dd++)
      acc[dd] += ctxs[(dg * 16 + dd) * 64 + e] * w;
  }
  unsigned short* op = ctx2t + ((size_t)b * 1024 + f) * 1024 + h * 64 + dg * 16;
#pragma unroll
  for (int g = 0; g < 4; g++){
    ushort4 o;
    o.x = f2bf(acc[g*4+0]); o.y = f2bf(acc[g*4+1]);
    o.z = f2bf(acc[g*4+2]); o.w = f2bf(acc[g*4+3]);
    *(ushort4*)&op[g*4] = o;
  }
}

extern "C" void kernel_launch(void* const* d_in, const int* in_sizes, int n_in,
                              void* d_out, int out_size, void* d_ws, size_t ws_size,
                              hipStream_t stream) {
  const float* x     = (const float*)d_in[0];  // [4,4096,1024]
  const float* w_qkv = (const float*)d_in[1];  // [1024,3072]
  const float* w_out = (const float*)d_in[2];  // [1024,1024]
  const float* b_out = (const float*)d_in[3];  // [1024]
  float* out = (float*)d_out;                  // [4,4096,1024] fp32

  const int M = 4 * SEQ;  // 16384

  unsigned short* xb = (unsigned short*)d_out;  // dead before gemm_final writes

  char* wp = (char*)d_ws;
  size_t off = 0;
  auto nxt = [&](size_t bytes) -> char* {
    char* p = wp + off;
    off += (bytes + 255) & ~(size_t)255;
    return p;
  };
  unsigned short* wqkvT = (unsigned short*)nxt((size_t)3072 * 1024 * 2);
  unsigned short* qt    = (unsigned short*)nxt((size_t)64 * 64 * SEQ * 2);
  unsigned short* kt    = (unsigned short*)nxt((size_t)64 * 64 * SEQ * 2);
  unsigned short* vb    = (unsigned short*)nxt((size_t)M * 1024 * 2);
  float*          ctxp  = (float*)wqkvT;       // aliases wqkvT (dead after qkv_gemm)
  unsigned short* ctx2t = qt;                  // aliases qt (dead after ctx_partial)

  // 1. converts
  cvt_f32_bf16<<<(M * 1024) / 4 / 256, 256, 0, stream>>>((const float4*)x, (ushort4*)xb);
  transpose_cvt<<<dim3(3072 / 64, 1024 / 64), 256, 0, stream>>>(w_qkv, wqkvT, 1024, 3072);

  // 2. fused qkv GEMM (256^2 tile, 1-barrier pipelined) -> qt, kt, vb
  qkv_gemm<<<768, 512, 0, stream>>>(xb, wqkvT, qt, kt, vb);

  // 3. context partials (fp32), 256 blocks
  ctx_partial<<<64 * 4, 256, 0, stream>>>(qt, kt, ctxp);

  // 4. ctx2t[b][f][hd]
  ctx2_kernel<<<64 * 16, 256, 0, stream>>>(ctxp, w_out, ctx2t);

  // 5. final batched GEMM (256^2 tile, 1-barrier pipelined)
  gemm_final<<<256, 512, 0, stream>>>(vb, ctx2t, out, b_out);
}

// Round 7
// 339.608 us; speedup vs baseline: 1.0279x; 1.0279x over previous
//
#include <hip/hip_runtime.h>
#include <hip/hip_bf16.h>

#define SEQ    4096
#define SCALE  0.125f

typedef __attribute__((ext_vector_type(8))) short s8v;
typedef __attribute__((ext_vector_type(8))) unsigned short u8v;
typedef __attribute__((ext_vector_type(4))) float f4v;

__device__ __forceinline__ unsigned short f2bf(float f){
  unsigned int u = __builtin_bit_cast(unsigned int, f);
  u += 0x7FFFu + ((u >> 16) & 1u);
  return (unsigned short)(u >> 16);
}

typedef const __attribute__((address_space(1))) unsigned int gl_uint;
typedef __attribute__((address_space(3))) unsigned int lds_uint;

__device__ __forceinline__ void gload_lds16(const unsigned short* g, unsigned short* l){
  __builtin_amdgcn_global_load_lds((gl_uint*)g, (lds_uint*)l, 16, 0, 0);
}

#define MM(a,b,c) __builtin_amdgcn_mfma_f32_16x16x32_bf16(a,b,c,0,0,0)
#define BAR() __builtin_amdgcn_s_barrier()
#define SB0() __builtin_amdgcn_sched_barrier(0)
#define VMW(n) asm volatile("s_waitcnt vmcnt(" #n ")" ::: "memory")

__device__ __forceinline__ void mfmaH0(const s8v (&A)[8], const s8v (&B)[4], f4v (&acc)[8][4]){
#pragma unroll
  for (int m = 0; m < 4; m++)
#pragma unroll
    for (int n = 0; n < 4; n++) acc[m][n] = MM(A[m], B[n], acc[m][n]);
}
__device__ __forceinline__ void mfmaH1(const s8v (&A)[8], const s8v (&B)[4], f4v (&acc)[8][4]){
#pragma unroll
  for (int m = 4; m < 8; m++)
#pragma unroll
    for (int n = 0; n < 4; n++) acc[m][n] = MM(A[m], B[n], acc[m][n]);
}

// ---------------- 256x256-tile GEMM mainloop, K=1024, BK=32, 8 waves (2Mx4N).
// A-ONLY LDS ring: 4 slots x 16 KB = 64 KiB (halves LDS pipe load: 640 cyc/tile
// vs MFMA 1024).  B comes straight from global in FRAGMENT-PACKED layout:
//   Bpk[(c>>4)*2048 + (k>>5)*64 + lane] (16B units), frag load = 64 lanes x 16B
//   contiguous global_load_dwordx4, L2-resident panel.
// One barrier per K-tile.  BODY(t): SB0;VMW(6);BAR;SB0; stage A(t+3);
// load B(t+1)->reg bank; ds_read A(t+1) halves interleaved with MFMA(t) halves.
// A(t+1)-residency proof: compiler MUST emit an in-order vmcnt wait for the
// B(t-1) registers before MFMA(t-1) (issued after A(t+1)'s staging ops), which
// retires A(t+1); SB0 pins MFMA(t-1)+wait before this body's barrier; barrier
// makes it collective.  VMW(6) is redundant insurance.
// A swizzle identical to round-4-verified (SQ_LDS_BANK_CONFLICT == 0).
__device__ __forceinline__ void mainloop_256(
    const unsigned short* __restrict__ Ag,
    const unsigned short* __restrict__ Bpk,
    int bm, int bn, f4v (&acc)[8][4])
{
  __shared__ __align__(16) unsigned short lds[32768];   // 64 KiB, A-only
  const int tid  = threadIdx.x;
  const int wave = tid >> 6, lane = tid & 63;
  const int quad = lane >> 4, l16 = lane & 15;
  const int wmi  = wave >> 2, wni = wave & 3;
  const char* ldsc = (const char*)lds;

  const int c16   = (quad ^ ((l16 >> 1) & 3)) * 16;     // verified swizzle
  const int abase = (wmi * 128 + l16) * 64 + c16;       // bytes within slot

  const int schunk = (((tid & 3) ^ ((tid >> 3) & 3)) * 8);
  const unsigned short* aS = Ag + (size_t)(bm + (tid >> 2)) * 1024 + schunk;
  unsigned short* ldsw = lds + wave * 512;              // wave-uniform base

  // packed-B per-wave pointer: frag nf at tile t -> bP + nf*16384 + t*512 (shorts)
  const unsigned short* bP = Bpk + ((size_t)((bn >> 4) + wni * 4) * 2048 + lane) * 8;

#define STG_A(t_) do{ unsigned short* d_ = ldsw + ((t_) & 3) * 8192; \
    const unsigned short* s_ = aS + (t_) * 32; \
    gload_lds16(s_, d_); gload_lds16(s_ + 128 * 1024, d_ + 4096); }while(0)

#define LDB(t_, BN) do{ \
    BN[0] = *(const s8v*)(bP +         (t_) * 512); \
    BN[1] = *(const s8v*)(bP + 16384 + (t_) * 512); \
    BN[2] = *(const s8v*)(bP + 32768 + (t_) * 512); \
    BN[3] = *(const s8v*)(bP + 49152 + (t_) * 512); }while(0)

#define LD_A4LO(NA, base_) do{ const char* p_ = (base_); \
    NA[0] = *(const s8v*)(p_ + abase);        NA[1] = *(const s8v*)(p_ + abase + 1024); \
    NA[2] = *(const s8v*)(p_ + abase + 2048); NA[3] = *(const s8v*)(p_ + abase + 3072); }while(0)
#define LD_A4HI(NA, base_) do{ const char* p_ = (base_); \
    NA[4] = *(const s8v*)(p_ + abase + 4096); NA[5] = *(const s8v*)(p_ + abase + 5120); \
    NA[6] = *(const s8v*)(p_ + abase + 6144); NA[7] = *(const s8v*)(p_ + abase + 7168); }while(0)

  s8v A0[8], B0[4], A1[8], B1[4];

  // prologue: A tiles 0..2 staged (6 ops), B tile 0 loaded (4 ops, 10 total);
  // VMW(8) retires A(0) -> slot 0 resident after BAR.
  STG_A(0); STG_A(1); STG_A(2);
  LDB(0, B0);
  VMW(8); BAR();
  LD_A4LO(A0, ldsc); LD_A4HI(A0, ldsc);

#define BODY(T_, CA, CB, NA, NB, DOSTG, DOLD) do{ \
    SB0(); VMW(6); BAR(); SB0(); \
    if (DOSTG) STG_A((T_) + 3); \
    if (DOLD)  LDB((T_) + 1, NB); \
    if (DOLD)  LD_A4LO(NA, ldsc + ((((T_) + 1) & 3) << 14)); \
    __builtin_amdgcn_s_setprio(1); mfmaH0(CA, CB, acc); __builtin_amdgcn_s_setprio(0); \
    if (DOLD)  LD_A4HI(NA, ldsc + ((((T_) + 1) & 3) << 14)); \
    __builtin_amdgcn_s_setprio(1); mfmaH1(CA, CB, acc); __builtin_amdgcn_s_setprio(0); \
  }while(0)

  for (int t = 0; t < 28; t += 2){
    BODY(t,     A0, B0, A1, B1, 1, 1);
    BODY(t + 1, A1, B1, A0, B0, 1, 1);
  }
  BODY(28, A0, B0, A1, B1, 1, 1);   // stages tile 31 (last)
  BODY(29, A1, B1, A0, B0, 0, 1);
  BODY(30, A0, B0, A1, B1, 0, 1);
  BODY(31, A1, B1, A0, B0, 0, 0);

#undef BODY
#undef LD_A4LO
#undef LD_A4HI
#undef LDB
#undef STG_A
}

// ---------------- qkv GEMM (fused q-softmax + k-exp), 256x256 tile
__global__ __launch_bounds__(512, 2) void qkv_gemm(
    const unsigned short* __restrict__ A,
    const unsigned short* __restrict__ Bpk,
    unsigned short* __restrict__ qt,
    unsigned short* __restrict__ kt,
    unsigned short* __restrict__ vb)
{
  const int id  = blockIdx.x;
  const int swz = (id & 7) * 96 + (id >> 3);     // 768 blocks, bijective XCD swizzle
  const int bm  = (swz / 12) * 256, bn = (swz % 12) * 256;

  f4v acc[8][4];
#pragma unroll
  for (int i = 0; i < 8; i++)
#pragma unroll
    for (int j = 0; j < 4; j++) acc[i][j] = (f4v){0.f,0.f,0.f,0.f};

  mainloop_256(A, Bpk, bm, bn, acc);

  const int tid = threadIdx.x;
  const int wave = tid >> 6, lane = tid & 63;
  const int quad = lane >> 4, l16 = lane & 15;
  const int wmi = wave >> 2, wni = wave & 3;
  const int colbase = bn + wni * 64;             // 64-aligned -> one head per wave
  const int rowbase = bm + wmi * 128;
  const int sec = colbase >> 10;                 // 0=q 1=k 2=v (wave-uniform)

  if (sec == 2){
#pragma unroll
    for (int nf = 0; nf < 4; nf++){
      int vc = colbase + nf * 16 + l16 - 2048;
#pragma unroll
      for (int mf = 0; mf < 8; mf++){
        int row = rowbase + mf * 16 + quad * 4;
#pragma unroll
        for (int r = 0; r < 4; r++)
          vb[(size_t)(row + r) * 1024 + vc] = f2bf(acc[mf][nf][r]);
      }
    }
    return;
  }

  if (sec == 0){
    // fused softmax over d (wave's 64 cols = full head)
#pragma unroll
    for (int mf = 0; mf < 8; mf++){
#pragma unroll
      for (int r = 0; r < 4; r++){
        float m = fmaxf(fmaxf(acc[mf][0][r], acc[mf][1][r]),
                        fmaxf(acc[mf][2][r], acc[mf][3][r]));
        for (int off = 8; off; off >>= 1) m = fmaxf(m, __shfl_xor(m, off));
        m *= SCALE;
        float e0 = __expf(acc[mf][0][r] * SCALE - m);
        float e1 = __expf(acc[mf][1][r] * SCALE - m);
        float e2 = __expf(acc[mf][2][r] * SCALE - m);
        float e3 = __expf(acc[mf][3][r] * SCALE - m);
        float s = (e0 + e1) + (e2 + e3);
        for (int off = 8; off; off >>= 1) s += __shfl_xor(s, off);
        float inv = 1.f / s;
        acc[mf][0][r] = e0 * inv; acc[mf][1][r] = e1 * inv;
        acc[mf][2][r] = e2 * inv; acc[mf][3][r] = e3 * inv;
      }
    }
#pragma unroll
    for (int nf = 0; nf < 4; nf++){
      int col = colbase + nf * 16 + l16;
      int h = (col >> 6) & 15, de = col & 63;
#pragma unroll
      for (int mf = 0; mf < 8; mf++){
        int row = rowbase + mf * 16 + quad * 4;
        int bb = row >> 12, nl = row & 4095;
        ushort4 o;
        o.x = f2bf(acc[mf][nf][0]); o.y = f2bf(acc[mf][nf][1]);
        o.z = f2bf(acc[mf][nf][2]); o.w = f2bf(acc[mf][nf][3]);
        *(ushort4*)&qt[(((size_t)bb * 16 + h) * 64 + de) * SEQ + nl] = o;
      }
    }
  } else {
    // k: exp per element; normalizer recovered in ctx2 (q cols sum to 1)
#pragma unroll
    for (int nf = 0; nf < 4; nf++){
      int col = colbase + nf * 16 + l16;
      int h = (col >> 6) & 15, de = col & 63;
#pragma unroll
      for (int mf = 0; mf < 8; mf++){
        int row = rowbase + mf * 16 + quad * 4;
        int bb = row >> 12, nl = row & 4095;
        ushort4 o;
        o.x = f2bf(__expf(acc[mf][nf][0])); o.y = f2bf(__expf(acc[mf][nf][1]));
        o.z = f2bf(__expf(acc[mf][nf][2])); o.w = f2bf(__expf(acc[mf][nf][3]));
        *(ushort4*)&kt[(((size_t)bb * 16 + h) * 64 + de) * SEQ + nl] = o;
      }
    }
  }
}

// ---------------- final batched GEMM: out[b] = vb[b] @ ctx2^T + bias, fp32
__global__ __launch_bounds__(512, 2) void gemm_final(
    const unsigned short* __restrict__ A,
    const unsigned short* __restrict__ C2pk,
    float* __restrict__ Cf,
    const float* __restrict__ bias)
{
  const int id  = blockIdx.x;
  const int swz = (id & 7) * 32 + (id >> 3);     // 256 blocks, bijective XCD swizzle
  const int bm  = (swz >> 2) * 256, bn = (swz & 3) * 256;
  const unsigned short* Bpk = C2pk + (size_t)(bm >> 12) * 1024 * 1024;

  f4v acc[8][4];
#pragma unroll
  for (int i = 0; i < 8; i++)
#pragma unroll
    for (int j = 0; j < 4; j++) acc[i][j] = (f4v){0.f,0.f,0.f,0.f};

  mainloop_256(A, Bpk, bm, bn, acc);

  const int tid = threadIdx.x;
  const int wave = tid >> 6, lane = tid & 63;
  const int quad = lane >> 4, l16 = lane & 15;
  const int wmi = wave >> 2, wni = wave & 3;

#pragma unroll
  for (int nf = 0; nf < 4; nf++){
    int col = bn + wni * 64 + nf * 16 + l16;
    float bv = bias[col];
#pragma unroll
    for (int mf = 0; mf < 8; mf++){
      int row = bm + wmi * 128 + mf * 16 + quad * 4;
#pragma unroll
      for (int r = 0; r < 4; r++)
        Cf[(size_t)(row + r) * 1024 + col] = acc[mf][nf][r] + bv;
    }
  }
}

// ---------------- fp32 -> bf16 elementwise (4/thread)
__global__ void cvt_f32_bf16(const float4* __restrict__ in, ushort4* __restrict__ outp){
  int i = blockIdx.x * 256 + threadIdx.x;
  float4 v = in[i];
  ushort4 o;
  o.x = f2bf(v.x); o.y = f2bf(v.y); o.z = f2bf(v.z); o.w = f2bf(v.w);
  outp[i] = o;
}

// ---------------- pack w_qkv [k=1024][c=3072] fp32 -> fragment-packed bf16:
// out 16B-unit index = (c>>4)*2048 + (k>>5)*64 + ((k>>3)&3)*16 + (c&15), elem k&7
__global__ __launch_bounds__(256) void pack_w(const float* __restrict__ in,
                                              unsigned short* __restrict__ outp){
  __shared__ float tile[64][65];
  int c0 = blockIdx.x * 64, k0 = blockIdx.y * 64;
  int t = threadIdx.x;
  for (int i = t; i < 4096; i += 256){ int k = i >> 6, c = i & 63;
    tile[k][c] = in[(size_t)(k0 + k) * 3072 + c0 + c]; }
  __syncthreads();
  for (int j = t; j < 512; j += 256){
    int c_l = j & 63, k8 = j >> 6;             // k8: 0..7 (8 consecutive k)
    int c = c0 + c_l, k = k0 + k8 * 8;
    u8v o;
#pragma unroll
    for (int e = 0; e < 8; e++) o[e] = f2bf(tile[k8 * 8 + e][c_l]);
    size_t idx = ((size_t)(c >> 4) * 2048 + (size_t)(k >> 5) * 64 +
                  ((k >> 3) & 3) * 16 + (c & 15)) * 8;
    *(u8v*)&outp[idx] = o;
  }
}

// ---------------- ctx partial: ctxp[bh*4+chunk][d*64+e] = sum_{n in chunk} qt[d,n] kt[e,n]
__global__ __launch_bounds__(256) void ctx_partial(const unsigned short* __restrict__ qt,
                                                   const unsigned short* __restrict__ kt,
                                                   float* __restrict__ ctxp){
  __shared__ float red[4096];
  int bh = blockIdx.x >> 2, ch = blockIdx.x & 3;
  int t = threadIdx.x, wave = t >> 6, lane = t & 63, quad = lane >> 4, l16 = lane & 15;
  const unsigned short* qb = qt + (size_t)bh * 64 * SEQ;
  const unsigned short* kb = kt + (size_t)bh * 64 * SEQ;
  f4v acc[4][4];
#pragma unroll
  for (int i = 0; i < 4; i++)
#pragma unroll
    for (int j = 0; j < 4; j++) acc[i][j] = (f4v){0.f,0.f,0.f,0.f};
  int ns = ch * 1024 + wave * 256;
  for (int n0 = ns; n0 < ns + 256; n0 += 32){
    s8v af[4], bf[4];
#pragma unroll
    for (int mt = 0; mt < 4; mt++) af[mt] = *(const s8v*)&qb[(size_t)(mt*16 + l16) * SEQ + n0 + quad*8];
#pragma unroll
    for (int nt = 0; nt < 4; nt++) bf[nt] = *(const s8v*)&kb[(size_t)(nt*16 + l16) * SEQ + n0 + quad*8];
#pragma unroll
    for (int mt = 0; mt < 4; mt++)
#pragma unroll
      for (int nt = 0; nt < 4; nt++)
        acc[mt][nt] = __builtin_amdgcn_mfma_f32_16x16x32_bf16(af[mt], bf[nt], acc[mt][nt], 0, 0, 0);
  }
  for (int i = t; i < 4096; i += 256) red[i] = 0.f;
  __syncthreads();
  for (int w = 0; w < 4; w++){
    if (wave == w){
#pragma unroll
      for (int mt = 0; mt < 4; mt++)
#pragma unroll
        for (int nt = 0; nt < 4; nt++)
#pragma unroll
          for (int r = 0; r < 4; r++)
            red[(mt*16 + quad*4 + r) * 64 + nt*16 + l16] += acc[mt][nt][r];
    }
    __syncthreads();
  }
  float* cp = ctxp + (size_t)blockIdx.x * 4096;
  for (int i = t; i < 4096; i += 256) cp[i] = red[i];
}

// ---------------- ctx2: fragment-packed B for gemm_final.
// logical B[b][f][k=h*64+d] = sum_e ctx[d][e]*inv[e]*w_out[h*64+e][f]; packed as
// 16B-unit (f>>4)*2048 + (k>>5)*64 + ((k>>3)&3)*16 + (f&15), elem k&7
__global__ __launch_bounds__(256) void ctx2_kernel(const float* __restrict__ ctxp,
                                                   const float* __restrict__ w_out,
                                                   unsigned short* __restrict__ ctx2t){
  __shared__ float ctxs[4096];
  __shared__ float inv_s[64];
  int bh = blockIdx.x >> 4, fc = blockIdx.x & 15;
  int b = bh >> 4, h = bh & 15;
  int t = threadIdx.x;
  int fl = t & 63, dg = t >> 6;
  int f = fc * 64 + fl;
  for (int i = t; i < 4096; i += 256){
    const float* p = ctxp + (size_t)bh * 4 * 4096 + i;
    ctxs[i] = (p[0] + p[4096]) + (p[8192] + p[12288]);
  }
  __syncthreads();
  if (t < 64){
    float s = 0.f;
#pragma unroll
    for (int d = 0; d < 64; d++) s += ctxs[d * 64 + t];
    inv_s[t] = 1.f / s;
  }
  __syncthreads();
  float acc[16];
#pragma unroll
  for (int i = 0; i < 16; i++) acc[i] = 0.f;
  for (int e = 0; e < 64; e++){
    float w = w_out[(size_t)(h * 64 + e) * 1024 + f] * inv_s[e];
#pragma unroll
    for (int dd = 0; dd < 16; dd++)
      acc[dd] += ctxs[(dg * 16 + dd) * 64 + e] * w;
  }
  unsigned short* base = ctx2t + (size_t)b * 1024 * 1024;
#pragma unroll
  for (int g = 0; g < 4; g++){
    int k = h * 64 + dg * 16 + g * 4;          // d index = dg*16+g*4 .. +3
    int kt = k >> 5, quad = (k >> 3) & 3, e0 = k & 7;   // e0 in {0,4}
    size_t idx = ((size_t)(f >> 4) * 2048 + (size_t)kt * 64 + quad * 16 + (f & 15)) * 8 + e0;
    ushort4 o;
    o.x = f2bf(acc[g*4+0]); o.y = f2bf(acc[g*4+1]);
    o.z = f2bf(acc[g*4+2]); o.w = f2bf(acc[g*4+3]);
    *(ushort4*)&base[idx] = o;
  }
}

extern "C" void kernel_launch(void* const* d_in, const int* in_sizes, int n_in,
                              void* d_out, int out_size, void* d_ws, size_t ws_size,
                              hipStream_t stream) {
  const float* x     = (const float*)d_in[0];  // [4,4096,1024]
  const float* w_qkv = (const float*)d_in[1];  // [1024,3072]
  const float* w_out = (const float*)d_in[2];  // [1024,1024]
  const float* b_out = (const float*)d_in[3];  // [1024]
  float* out = (float*)d_out;                  // [4,4096,1024] fp32

  const int M = 4 * SEQ;  // 16384

  unsigned short* xb = (unsigned short*)d_out;  // dead before gemm_final writes

  char* wp = (char*)d_ws;
  size_t off = 0;
  auto nxt = [&](size_t bytes) -> char* {
    char* p = wp + off;
    off += (bytes + 255) & ~(size_t)255;
    return p;
  };
  unsigned short* wqkvP = (unsigned short*)nxt((size_t)3072 * 1024 * 2);   // packed B, 6 MiB
  unsigned short* qt    = (unsigned short*)nxt((size_t)64 * 64 * SEQ * 2); // 32 MiB
  unsigned short* kt    = (unsigned short*)nxt((size_t)64 * 64 * SEQ * 2); // 32 MiB
  unsigned short* vb    = (unsigned short*)nxt((size_t)M * 1024 * 2);      // 32 MiB
  float*          ctxp  = (float*)wqkvP;       // aliases wqkvP (dead after qkv_gemm)
  unsigned short* ctx2t = qt;                  // aliases qt (dead after ctx_partial)

  // 1. converts / packs
  cvt_f32_bf16<<<(M * 1024) / 4 / 256, 256, 0, stream>>>((const float4*)x, (ushort4*)xb);
  pack_w<<<dim3(3072 / 64, 1024 / 64), 256, 0, stream>>>(w_qkv, wqkvP);

  // 2. fused qkv GEMM (A via LDS, B packed from L2) -> qt, kt, vb
  qkv_gemm<<<768, 512, 0, stream>>>(xb, wqkvP, qt, kt, vb);

  // 3. context partials (fp32), 256 blocks
  ctx_partial<<<64 * 4, 256, 0, stream>>>(qt, kt, ctxp);

  // 4. ctx2 -> fragment-packed B for gemm_final
  ctx2_kernel<<<64 * 16, 256, 0, stream>>>(ctxp, w_out, ctx2t);

  // 5. final batched GEMM
  gemm_final<<<256, 512, 0, stream>>>(vb, ctx2t, out, b_out);
}